// Round 1
// baseline (14664.420 us; speedup 1.0000x reference)
//
#include <hip/hip_runtime.h>

// Problem constants
#define B_    64
#define S_    2048
#define E_    512
#define H_    256
#define NBLK  32            // feature blocks per direction
#define TB    256           // threads per block
#define WROWS 32            // gate rows per block (4 gates x 8 h-cols)
#define HC    8             // h columns per block
#define KTOT  768           // E + H
#define LDW   776           // padded LDS row (768 + 8) -> 2-way-bank-free
#define RING_ELE (B_ * H_)  // 16384 bf16 per ring slot

typedef __attribute__((ext_vector_type(8))) short short8;
typedef __attribute__((ext_vector_type(4))) float f32x4;

__device__ __forceinline__ unsigned short f2bf(float f) {
    unsigned u = __builtin_bit_cast(unsigned, f);
    u += 0x7FFFu + ((u >> 16) & 1u);       // round-to-nearest-even
    return (unsigned short)(u >> 16);
}
__device__ __forceinline__ float sigm(float x) { return 1.0f / (1.0f + __expf(-x)); }
__device__ __forceinline__ float tanh_fast(float x) {
    float ax = fabsf(x);
    float e = __expf(-2.0f * ax);
    float t = (1.0f - e) / (1.0f + e);
    return x < 0.0f ? -t : t;
}

// Phase 0: x fp32 [B,S,E] -> bf16 time-major [S,B,E]
__global__ void cvt_x_kernel(const float* __restrict__ x, unsigned short* __restrict__ xb) {
    unsigned i = blockIdx.x * TB + threadIdx.x;       // B*S*E/4 threads
    unsigned e4 = i & (E_ / 4 - 1);                   // 128 float4 groups per row
    unsigned rest = i >> 7;
    unsigned s = rest & (S_ - 1);
    unsigned b = rest >> 11;
    const float4 v = *(const float4*)(x + (size_t)(b * S_ + s) * E_ + e4 * 4);
    ushort4 o;
    o.x = f2bf(v.x); o.y = f2bf(v.y); o.z = f2bf(v.z); o.w = f2bf(v.w);
    *(ushort4*)(xb + (size_t)(s * B_ + b) * E_ + e4 * 4) = o;
}

// Phase 0b: initial h -> ring slot 1 (consumed at t=0)
__global__ void init_h_kernel(const float* __restrict__ h0f, const float* __restrict__ h0b,
                              unsigned short* __restrict__ ring) {
    unsigned i = blockIdx.x * TB + threadIdx.x;       // 2*B*H threads
    unsigned d = i >> 14;
    unsigned idx = i & 16383;
    const float* src = d ? h0b : h0f;
    ring[(d * 2 + 1) * RING_ELE + idx] = f2bf(src[idx]);
}

// Phase 1: persistent bidirectional LSTM. 64 blocks: [0,32)=fwd, [32,64)=bwd.
// Block (d,g) owns h-cols [g*8, g*8+8) i.e. gate rows {q*256 + g*8 + j}.
//
// Sync protocol (fence-free): all cross-block data (h ring) moves via relaxed
// AGENT-scope atomics, which are sc1 accesses at the LLC coherence point.
// Producer: h stores -> s_waitcnt vmcnt(0) (+barrier) -> flag[g] = t+1 (relaxed store).
// Consumer: lane-parallel poll flag[0..31] >= t -> barrier -> h loads (relaxed).
// No release RMW (no serialized LLC read-modify-write chain), no acquire fence
// (no per-step L1/L2 invalidate), no release fence (no per-step dirty-L2 writeback).
__global__ __launch_bounds__(TB, 1) void lstm_seq_kernel(
    const unsigned short* __restrict__ xb,
    unsigned short* __restrict__ ring,
    int* __restrict__ flags,
    float* __restrict__ out,
    const float* __restrict__ wih_f, const float* __restrict__ whh_f,
    const float* __restrict__ bih_f, const float* __restrict__ bhh_f,
    const float* __restrict__ wih_b, const float* __restrict__ whh_b,
    const float* __restrict__ bih_b, const float* __restrict__ bhh_b,
    const float* __restrict__ c0_f, const float* __restrict__ c0_b)
{
    __shared__ unsigned short lds_w[WROWS * LDW];   // 49,664 B: [32][776] bf16 (W_ih | W_hh)
    __shared__ float lds_g[B_ * 36];                // 9,216 B: gates [64][36]

    const int tid = threadIdx.x;
    const int bid = blockIdx.x;
    const int d = bid >> 5;
    const int g = bid & (NBLK - 1);
    const float* wih = d ? wih_b : wih_f;
    const float* whh = d ? whh_b : whh_f;
    const float* bih = d ? bih_b : bih_f;
    const float* bhh = d ? bhh_b : bhh_f;
    const float* c0p = d ? c0_b : c0_f;

    // Load combined weight slice [32][768] into LDS (bf16)
    for (int idx = tid; idx < WROWS * KTOT; idx += TB) {
        int r = idx / KTOT;
        int k = idx - r * KTOT;
        int gr = (r >> 3) * H_ + g * HC + (r & 7);   // global gate row
        float v = (k < E_) ? wih[(size_t)gr * E_ + k] : whh[(size_t)gr * H_ + (k - E_)];
        lds_w[r * LDW + k] = f2bf(v);
    }

    const int lane = tid & 63;
    const int wave = tid >> 6;          // wave = M-tile (batches wave*16..+16)
    const int nc = lane & 15;           // fragment col within 16
    const int kq = (lane >> 4) * 8;     // k-quad offset

    const int gr0 = ((nc) >> 3) * H_ + g * HC + (nc & 7);
    const int gr1 = ((16 + nc) >> 3) * H_ + g * HC + ((16 + nc) & 7);
    const float bias0 = bih[gr0] + bhh[gr0];
    const float bias1 = bih[gr1] + bhh[gr1];

    // c state in regs: thread covers flattened [64][8] elements 2*tid, 2*tid+1
    const int cb = tid >> 2;
    const int cj = (2 * tid) & 7;
    float creg0 = c0p[cb * H_ + g * HC + cj];
    float creg1 = c0p[cb * H_ + g * HC + cj + 1];

    unsigned short* ringd = ring + d * 2 * RING_ELE;
    int* flagd = flags + d * NBLK;      // one 128 B line per direction

    f32x4 acc0, acc1;
    #pragma unroll
    for (int r = 0; r < 4; ++r) { acc0[r] = bias0; acc1[r] = bias1; }

    const unsigned short* brow0 = lds_w + nc * LDW + kq;
    const unsigned short* brow1 = lds_w + (16 + nc) * LDW + kq;
    const int m = wave * 16 + nc;       // batch row this lane's A-fragment covers

    __syncthreads();   // weights visible

    for (int t = 0; t < S_; ++t) {
        const int s = d ? (S_ - 1 - t) : t;

        // --- phase A: input projection, A-fragments straight from global ---
        // (runs before the wait: overlaps the producers' signal propagation)
        const unsigned short* xrow = xb + (size_t)s * (B_ * E_) + m * E_ + kq;
        #pragma unroll
        for (int k = 0; k < E_; k += 32) {
            short8 a  = *(const short8*)(xrow + k);
            short8 b0 = *(const short8*)(brow0 + k);
            short8 b1 = *(const short8*)(brow1 + k);
            acc0 = __builtin_amdgcn_mfma_f32_16x16x32_bf16(a, b0, acc0, 0, 0, 0);
            acc1 = __builtin_amdgcn_mfma_f32_16x16x32_bf16(a, b1, acc1, 0, 0, 0);
        }

        // --- wait for h(t-1): lane-parallel poll of 32 per-producer flags ---
        if (t > 0 && tid < NBLK) {
            const int* fp = flagd + tid;
            int v;
            do {
                v = __hip_atomic_load(fp, __ATOMIC_RELAXED, __HIP_MEMORY_SCOPE_AGENT);
                if (v < t) __builtin_amdgcn_s_sleep(1);
            } while (v < t);
        }
        __syncthreads();   // poll result visible to all waves; orders h loads after it

        // --- phase B: recurrent part, h fragments via agent-scope atomic loads (LLC-coherent) ---
        {
            unsigned long long* hsrc =
                (unsigned long long*)(ringd + ((t & 1) ^ 1) * RING_ELE);
            const int hbase = (m * H_ + kq) >> 2;    // ulong units
            #pragma unroll
            for (int ks = 0; ks < 8; ++ks) {
                union { unsigned long long u[2]; short8 v; } af;
                af.u[0] = __hip_atomic_load(hsrc + hbase + ks * 8,     __ATOMIC_RELAXED, __HIP_MEMORY_SCOPE_AGENT);
                af.u[1] = __hip_atomic_load(hsrc + hbase + ks * 8 + 1, __ATOMIC_RELAXED, __HIP_MEMORY_SCOPE_AGENT);
                short8 b0 = *(const short8*)(brow0 + E_ + ks * 32);
                short8 b1 = *(const short8*)(brow1 + E_ + ks * 32);
                acc0 = __builtin_amdgcn_mfma_f32_16x16x32_bf16(af.v, b0, acc0, 0, 0, 0);
                acc1 = __builtin_amdgcn_mfma_f32_16x16x32_bf16(af.v, b1, acc1, 0, 0, 0);
            }
        }

        // --- gates to LDS (C-layout: col=lane&15, row=(lane>>4)*4+reg) ---
        #pragma unroll
        for (int r = 0; r < 4; ++r) {
            int row = wave * 16 + (lane >> 4) * 4 + r;
            lds_g[row * 36 + nc]      = acc0[r];
            lds_g[row * 36 + 16 + nc] = acc1[r];
        }
        __syncthreads();

        // --- pointwise LSTM cell: 2 (batch, h-col) elements per thread ---
        float gi0 = sigm(lds_g[cb * 36 + cj]);
        float gf0 = sigm(lds_g[cb * 36 + 8 + cj]);
        float gg0 = tanh_fast(lds_g[cb * 36 + 16 + cj]);
        float go0 = sigm(lds_g[cb * 36 + 24 + cj]);
        float gi1 = sigm(lds_g[cb * 36 + cj + 1]);
        float gf1 = sigm(lds_g[cb * 36 + 8 + cj + 1]);
        float gg1 = tanh_fast(lds_g[cb * 36 + 16 + cj + 1]);
        float go1 = sigm(lds_g[cb * 36 + 24 + cj + 1]);
        creg0 = gf0 * creg0 + gi0 * gg0;
        creg1 = gf1 * creg1 + gi1 * gg1;
        float h0v = go0 * tanh_fast(creg0);
        float h1v = go1 * tanh_fast(creg1);

        // h -> ring slot t&1 (bf16x2, agent-scope atomic store -> lands at LLC)
        unsigned hp = (unsigned)f2bf(h0v) | ((unsigned)f2bf(h1v) << 16);
        __hip_atomic_store((unsigned*)(ringd + (t & 1) * RING_ELE + cb * H_ + g * HC + cj), hp,
                           __ATOMIC_RELAXED, __HIP_MEMORY_SCOPE_AGENT);
        // out[b][s][d*H + col] fp32 (full-precision h)
        float2 ov; ov.x = h0v; ov.y = h1v;
        *(float2*)(out + ((size_t)cb * S_ + s) * (2 * H_) + d * H_ + g * HC + cj) = ov;

        // re-init accumulators with bias for next step
        #pragma unroll
        for (int r = 0; r < 4; ++r) { acc0[r] = bias0; acc1[r] = bias1; }

        // Publish: drain this thread's h store to the LLC, barrier so ALL
        // threads' stores are drained, then one relaxed flag store.
        asm volatile("s_waitcnt vmcnt(0)" ::: "memory");
        __syncthreads();
        if (tid == 0)
            __hip_atomic_store(flagd + g, t + 1, __ATOMIC_RELAXED, __HIP_MEMORY_SCOPE_AGENT);
    }
}

extern "C" void kernel_launch(void* const* d_in, const int* in_sizes, int n_in,
                              void* d_out, int out_size, void* d_ws, size_t ws_size,
                              hipStream_t stream) {
    (void)in_sizes; (void)n_in; (void)out_size; (void)ws_size;
    const float* x     = (const float*)d_in[0];
    const float* wih_f = (const float*)d_in[1];
    const float* whh_f = (const float*)d_in[2];
    const float* bih_f = (const float*)d_in[3];
    const float* bhh_f = (const float*)d_in[4];
    const float* wih_b = (const float*)d_in[5];
    const float* whh_b = (const float*)d_in[6];
    const float* bih_b = (const float*)d_in[7];
    const float* bhh_b = (const float*)d_in[8];
    const float* h0_f  = (const float*)d_in[9];
    const float* c0_f  = (const float*)d_in[10];
    const float* h0_b  = (const float*)d_in[11];
    const float* c0_b  = (const float*)d_in[12];
    float* out = (float*)d_out;

    // workspace layout
    char* ws = (char*)d_ws;
    int* flags = (int*)ws;                                          // 16,384 B reserved (uses 256 B)
    unsigned short* ring = (unsigned short*)(ws + 16384);           // 131,072 B
    unsigned short* xb   = (unsigned short*)(ws + 16384 + 131072);  // 134,217,728 B

    hipMemsetAsync(flags, 0, 2 * NBLK * sizeof(int), stream);
    cvt_x_kernel<<<(B_ * S_ * E_ / 4) / TB, TB, 0, stream>>>(x, xb);
    init_h_kernel<<<(2 * B_ * H_) / TB, TB, 0, stream>>>(h0_f, h0_b, ring);
    lstm_seq_kernel<<<2 * NBLK, TB, 0, stream>>>(xb, ring, flags, out,
                                                 wih_f, whh_f, bih_f, bhh_f,
                                                 wih_b, whh_b, bih_b, bhh_b,
                                                 c0_f, c0_b);
}